// Round 1
// baseline (27832.776 us; speedup 1.0000x reference)
//
#include <hip/hip_runtime.h>
#include <math.h>

#define B_ 20
#define S_ 256
#define V_ 32000
#define H_ 1024
#define G_ 4096  // 4*H

// ---------------------------------------------------------------------------
// Embedding gather: xs[s][b][:] = emb[ids[b][s]][:]
// ---------------------------------------------------------------------------
__global__ __launch_bounds__(256) void embed_kernel(const int* __restrict__ ids,
                                                    const float* __restrict__ emb,
                                                    float* __restrict__ xs) {
    int idx = blockIdx.x * 256 + threadIdx.x;        // over S*B*(H/4)
    int total = S_ * B_ * (H_ / 4);
    if (idx >= total) return;
    int h4 = idx % (H_ / 4);
    int sb = idx / (H_ / 4);
    int b = sb % B_;
    int s = sb / B_;
    int tok = ids[b * S_ + s];
    const float4* src = (const float4*)(emb + (long)tok * H_);
    float4* dst = (float4*)(xs + (long)sb * H_);
    dst[h4] = src[h4];
}

// ---------------------------------------------------------------------------
// C[M,N] = A[M,K] @ B[N,K]^T + bias[N]
// out_mode 0: C row r at C + r*N
// out_mode 1: decoder remap: r = s*B_+b  ->  C + (b*S_+s)*N   (logits [B,S,V])
// M,N divisible by 64; K divisible by 16.
// ---------------------------------------------------------------------------
#define BM 64
#define BN 64
#define BK 16
__global__ __launch_bounds__(256) void gemm_bt(const float* __restrict__ A,
                                               const float* __restrict__ Bm,
                                               const float* __restrict__ bias,
                                               float* __restrict__ C,
                                               int M, int N, int K, int out_mode) {
    __shared__ float As[BK][BM];
    __shared__ float Bs[BK][BN];
    const int bn = blockIdx.x, bm = blockIdx.y;
    const int tid = threadIdx.x;
    const int tx = tid % 16, ty = tid / 16;

    const float* Ab = A + (long)bm * BM * K;
    const float* Bb = Bm + (long)bn * BN * K;

    const int lr = tid / 4;            // 0..63 tile row
    const int lk = (tid % 4) * 4;      // 0,4,8,12

    float acc[4][4] = {};

    for (int k0 = 0; k0 < K; k0 += BK) {
        float4 av = *(const float4*)(Ab + (long)lr * K + k0 + lk);
        float4 bv = *(const float4*)(Bb + (long)lr * K + k0 + lk);
        As[lk + 0][lr] = av.x; As[lk + 1][lr] = av.y;
        As[lk + 2][lr] = av.z; As[lk + 3][lr] = av.w;
        Bs[lk + 0][lr] = bv.x; Bs[lk + 1][lr] = bv.y;
        Bs[lk + 2][lr] = bv.z; Bs[lk + 3][lr] = bv.w;
        __syncthreads();
        #pragma unroll
        for (int k = 0; k < BK; ++k) {
            float4 a = *(const float4*)&As[k][ty * 4];
            float4 b = *(const float4*)&Bs[k][tx * 4];
            acc[0][0] += a.x * b.x; acc[0][1] += a.x * b.y; acc[0][2] += a.x * b.z; acc[0][3] += a.x * b.w;
            acc[1][0] += a.y * b.x; acc[1][1] += a.y * b.y; acc[1][2] += a.y * b.z; acc[1][3] += a.y * b.w;
            acc[2][0] += a.z * b.x; acc[2][1] += a.z * b.y; acc[2][2] += a.z * b.z; acc[2][3] += a.z * b.w;
            acc[3][0] += a.w * b.x; acc[3][1] += a.w * b.y; acc[3][2] += a.w * b.z; acc[3][3] += a.w * b.w;
        }
        __syncthreads();
    }

    const int col0 = bn * BN + tx * 4;
    float4 bb = *(const float4*)(bias + col0);
    #pragma unroll
    for (int i = 0; i < 4; ++i) {
        int r = bm * BM + ty * 4 + i;
        float4 v;
        v.x = acc[i][0] + bb.x; v.y = acc[i][1] + bb.y;
        v.z = acc[i][2] + bb.z; v.w = acc[i][3] + bb.w;
        long row;
        if (out_mode == 0) row = (long)r;
        else { int b = r % B_; int s = r / B_; row = (long)b * S_ + s; }
        *(float4*)(C + row * N + col0) = v;
    }
}

// ---------------------------------------------------------------------------
// One LSTM time step. grid = H_/4 = 256 blocks; block owns 4 h-columns
// (j0..j0+3) and computes all 4 gates for them across the 20-row batch.
// gates = xp[t] + h_prev @ Wh^T + bh ; i,f,g,o chunks of size H_.
// ---------------------------------------------------------------------------
__global__ __launch_bounds__(256) void lstm_step(const float* __restrict__ xp,      // [B,4H] (pre-offset to step t)
                                                 const float* __restrict__ h_prev,  // [B,H]
                                                 const float* __restrict__ c_prev,  // [B,H]
                                                 const float* __restrict__ Wh,      // [4H,H]
                                                 const float* __restrict__ bh,      // [4H]
                                                 float* __restrict__ h_out,         // [B,H]
                                                 float* __restrict__ c_out) {       // [B,H]
    __shared__ float hs[B_ * H_];        // 80 KB
    __shared__ float gv[4][4][B_ + 1];   // gate, jj, b
    const int tid = threadIdx.x;

    float4* hs4 = (float4*)hs;
    const float4* hp4 = (const float4*)h_prev;
    for (int i = tid; i < B_ * H_ / 4; i += 256) hs4[i] = hp4[i];
    __syncthreads();

    const int j0 = blockIdx.x * 4;
    for (int o = tid; o < 320; o += 256) {
        int b = o % B_;
        int jj = (o / B_) % 4;
        int gate = o / (B_ * 4);
        int row = gate * H_ + j0 + jj;
        const float4* w4 = (const float4*)(Wh + (long)row * H_);
        const float4* h4 = (const float4*)(hs + b * H_);
        float sum = 0.f;
        #pragma unroll 4
        for (int d = 0; d < H_ / 4; ++d) {
            float4 w = w4[d];
            float4 h = h4[d];
            sum += w.x * h.x + w.y * h.y + w.z * h.z + w.w * h.w;
        }
        sum += xp[b * G_ + row] + bh[row];
        gv[gate][jj][b] = sum;
    }
    __syncthreads();

    if (tid < 4 * B_) {
        int b = tid % B_;
        int jj = tid / B_;
        int j = j0 + jj;
        float iv = gv[0][jj][b], fv = gv[1][jj][b], gvv = gv[2][jj][b], ov = gv[3][jj][b];
        iv = 1.f / (1.f + expf(-iv));
        fv = 1.f / (1.f + expf(-fv));
        gvv = tanhf(gvv);
        ov = 1.f / (1.f + expf(-ov));
        float c = c_prev[b * H_ + j] * fv + iv * gvv;
        c_out[b * H_ + j] = c;
        h_out[b * H_ + j] = ov * tanhf(c);
    }
}

// ---------------------------------------------------------------------------
// Final states -> d_out tail: h1, c1, h2, c2 each [B,H]
// ---------------------------------------------------------------------------
__global__ __launch_bounds__(256) void copy_states(const float* __restrict__ h1,
                                                   const float* __restrict__ c1,
                                                   const float* __restrict__ h2,
                                                   const float* __restrict__ c2,
                                                   float* __restrict__ out) {
    int i = blockIdx.x * 256 + threadIdx.x;
    if (i < B_ * H_) {
        out[i] = h1[i];
        out[B_ * H_ + i] = c1[i];
        out[2 * B_ * H_ + i] = h2[i];
        out[3 * B_ * H_ + i] = c2[i];
    }
}

extern "C" void kernel_launch(void* const* d_in, const int* in_sizes, int n_in,
                              void* d_out, int out_size, void* d_ws, size_t ws_size,
                              hipStream_t stream) {
    const int*   ids    = (const int*)  d_in[0];
    const float* emb    = (const float*)d_in[1];
    const float* x2h_w1 = (const float*)d_in[2];
    const float* x2h_b1 = (const float*)d_in[3];
    const float* h2h_w1 = (const float*)d_in[4];
    const float* h2h_b1 = (const float*)d_in[5];
    const float* x2h_w2 = (const float*)d_in[6];
    const float* x2h_b2 = (const float*)d_in[7];
    const float* h2h_w2 = (const float*)d_in[8];
    const float* h2h_b2 = (const float*)d_in[9];
    const float* dec_w  = (const float*)d_in[10];
    const float* dec_b  = (const float*)d_in[11];
    const float* h01    = (const float*)d_in[12];
    const float* c01    = (const float*)d_in[13];
    const float* h02    = (const float*)d_in[14];
    const float* c02    = (const float*)d_in[15];

    float* logits = (float*)d_out;                         // [B,S,V]
    float* states = logits + (long)B_ * S_ * V_;           // h1,c1,h2,c2

    // workspace layout (floats)
    float* ws   = (float*)d_ws;
    float* xp   = ws;                                      // [S*B, 4H]  (reused L1 then L2)
    float* out1 = xp + (long)S_ * B_ * G_;                 // [S,B,H]
    float* xs   = out1 + (long)S_ * B_ * H_;               // [S,B,H]  (embeds, later reused as out2)
    float* out2 = xs;                                      // alias: xs dead after xproj1
    float* cb   = xs + (long)S_ * B_ * H_;                 // 4 ping-pong c buffers [B,H]
    float* c1_0 = cb;
    float* c1_1 = cb + B_ * H_;
    float* c2_0 = cb + 2 * B_ * H_;
    float* c2_1 = cb + 3 * B_ * H_;

    const int M = S_ * B_;  // 5120

    // 1) embedding
    {
        int total = S_ * B_ * (H_ / 4);
        embed_kernel<<<(total + 255) / 256, 256, 0, stream>>>(ids, emb, xs);
    }

    // 2) xproj layer 1: xp = xs @ x2h_w1^T + b
    gemm_bt<<<dim3(G_ / BN, M / BM), 256, 0, stream>>>(xs, x2h_w1, x2h_b1, xp, M, G_, H_, 0);

    // 3) layer-1 recurrence
    for (int t = 0; t < S_; ++t) {
        const float* hp = (t == 0) ? h01 : (out1 + (long)(t - 1) * B_ * H_);
        const float* cp = (t == 0) ? c01 : ((t & 1) ? c1_0 : c1_1);
        float* cw = (t & 1) ? c1_1 : c1_0;
        lstm_step<<<H_ / 4, 256, 0, stream>>>(xp + (long)t * B_ * G_, hp, cp,
                                              h2h_w1, h2h_b1,
                                              out1 + (long)t * B_ * H_, cw);
    }

    // 4) xproj layer 2: xp = out1 @ x2h_w2^T + b   (overwrites xp)
    gemm_bt<<<dim3(G_ / BN, M / BM), 256, 0, stream>>>(out1, x2h_w2, x2h_b2, xp, M, G_, H_, 0);

    // 5) layer-2 recurrence
    for (int t = 0; t < S_; ++t) {
        const float* hp = (t == 0) ? h02 : (out2 + (long)(t - 1) * B_ * H_);
        const float* cp = (t == 0) ? c02 : ((t & 1) ? c2_0 : c2_1);
        float* cw = (t & 1) ? c2_1 : c2_0;
        lstm_step<<<H_ / 4, 256, 0, stream>>>(xp + (long)t * B_ * G_, hp, cp,
                                              h2h_w2, h2h_b2,
                                              out2 + (long)t * B_ * H_, cw);
    }

    // 6) decoder: logits[b,s,:] = out2[s,b,:] @ dec_w^T + dec_b
    gemm_bt<<<dim3(V_ / BN, M / BM), 256, 0, stream>>>(out2, dec_w, dec_b, logits, M, V_, H_, 1);

    // 7) final states (S_=256 even -> last write parity is buffer _1)
    copy_states<<<(B_ * H_ + 255) / 256, 256, 0, stream>>>(
        out1 + (long)(S_ - 1) * B_ * H_, c1_1,
        out2 + (long)(S_ - 1) * B_ * H_, c2_1, states);
}